// Round 5
// baseline (792.839 us; speedup 1.0000x reference)
//
#include <hip/hip_runtime.h>
#include <stdint.h>

#define TOKENS 8192
#define HIDDEN 2048
#define INTER  5632

typedef _Float16 f16x8  __attribute__((ext_vector_type(8)));
typedef _Float16 f16x2  __attribute__((ext_vector_type(2)));
typedef float    f32x16 __attribute__((ext_vector_type(16)));
typedef unsigned int uint;

// async global->LDS, 16B per lane. LDS dest = wave-uniform base + lane*16.
__device__ __forceinline__ void async_copy16(const void* g, void* l) {
  __builtin_amdgcn_global_load_lds(
      (const __attribute__((address_space(1))) uint*)g,
      (__attribute__((address_space(3))) uint*)l, 16, 0, 0);
}

// ---- int4 -> f16x8 in-register dequant, EXACT form -------------------------
// (q|0x6400) as f16 == 1024+q exactly; minus z1=(1025+z) is exact (Sterbenz,
// both in [1024,2048)); then * s with a single rounding. (The fma-with-
// precomputed-bias variant rounds (1025+z)*s to f16 -> group-correlated
// weight error ~0.8% -> absmax 68 at round 4. Keep the exact form.)
// Output j-order: k0,k4,k1,k5,k2,k6,k3,k7 — A staging uses the same perm.
union U8 { uint u[4]; f16x8 v; };
__device__ __forceinline__ f16x8 dq8(uint w, uint sd, uint zd) {
  const f16x2 s = __builtin_bit_cast(f16x2, sd);
  const f16x2 z = __builtin_bit_cast(f16x2, zd);
  uint t0 = ( w        & 0x000F000Fu) | 0x64006400u;
  uint t1 = ((w >> 4)  & 0x000F000Fu) | 0x64006400u;
  uint t2 = ((w >> 8)  & 0x000F000Fu) | 0x64006400u;
  uint t3 = ((w >> 12) & 0x000F000Fu) | 0x64006400u;
  U8 r;
  r.u[0] = __builtin_bit_cast(uint, (f16x2)((__builtin_bit_cast(f16x2, t0) - z) * s));
  r.u[1] = __builtin_bit_cast(uint, (f16x2)((__builtin_bit_cast(f16x2, t1) - z) * s));
  r.u[2] = __builtin_bit_cast(uint, (f16x2)((__builtin_bit_cast(f16x2, t2) - z) * s));
  r.u[3] = __builtin_bit_cast(uint, (f16x2)((__builtin_bit_cast(f16x2, t3) - z) * s));
  return r.v;
}

__device__ __forceinline__ uint dupf16(float x) {
  _Float16 h = (_Float16)x;
  unsigned short bb = __builtin_bit_cast(unsigned short, h);
  return (uint)bb * 0x00010001u;
}

// x [T,H] fp32 -> staged [T/128][H/8][128][8] f16, k-permuted (k0,k4,k1,k5,..)
__global__ void k_convert_x(const float* __restrict__ x, _Float16* __restrict__ xs) {
  const int kb = blockIdx.x;            // H/8 = 256
  const int mt = blockIdx.y;            // T/128 = 64
  const int m  = threadIdx.x;           // 128
  const float* src = x + (size_t)(mt * 128 + m) * HIDDEN + kb * 8;
  float4 f0 = *(const float4*)src;
  float4 f1 = *(const float4*)(src + 4);
  f16x8 v;
  v[0] = (_Float16)f0.x; v[1] = (_Float16)f1.x;
  v[2] = (_Float16)f0.y; v[3] = (_Float16)f1.y;
  v[4] = (_Float16)f0.z; v[5] = (_Float16)f1.z;
  v[6] = (_Float16)f0.w; v[7] = (_Float16)f1.w;
  *(f16x8*)(xs + ((size_t)(mt * 256 + kb) * 128 + m) * 8) = v;
}

// sz tables: per (group, n): dup-f16 {s, 1025+z}
__global__ void k_prep_szgu(const uint* __restrict__ gz, const float* __restrict__ gs,
                            const uint* __restrict__ uz, const float* __restrict__ us,
                            uint4* __restrict__ out) {
  const int n = blockIdx.x * 256 + threadIdx.x;   // 5632
  const int g = blockIdx.y;                        // 16
  const int sh = (n & 7) * 4;
  int zg = (int)((gz[(size_t)g * (INTER / 8) + (n >> 3)] >> sh) & 0xFu);
  int zu = (int)((uz[(size_t)g * (INTER / 8) + (n >> 3)] >> sh) & 0xFu);
  float sg = gs[(size_t)g * INTER + n];
  float su = us[(size_t)g * INTER + n];
  out[(size_t)g * INTER + n] =
      make_uint4(dupf16(sg), dupf16((float)(1025 + zg)),
                 dupf16(su), dupf16((float)(1025 + zu)));
}

__global__ void k_prep_szd(const uint* __restrict__ dz, const float* __restrict__ ds,
                           uint2* __restrict__ out) {
  const int n = blockIdx.x * 256 + threadIdx.x;   // 2048
  const int g = blockIdx.y;                        // 44
  const int sh = (n & 7) * 4;
  int z = (int)((dz[(size_t)g * (HIDDEN / 8) + (n >> 3)] >> sh) & 0xFu);
  float s = ds[(size_t)g * HIDDEN + n];
  out[(size_t)g * HIDDEN + n] = make_uint2(dupf16(s), dupf16((float)(1025 + z)));
}

// GEMM1: h = silu(x@Wg) * (x@Wu). 128x128 tile, BK=64, mfma 32x32x16.
// 4 waves, wave w = full 128 M x 32 N (cols [32w,32w+32)) -> zero dequant dup.
__global__ __launch_bounds__(256, 2)
void k_gemm_gateup(const _Float16* __restrict__ xs,
                   const uint* __restrict__ gq,
                   const uint* __restrict__ uq,
                   const uint4* __restrict__ szgu,
                   _Float16* __restrict__ hs) {
  __shared__ char smem[16384 + 4096 + 4096 + 2048];
  _Float16* Al = (_Float16*)smem;          // [8 kb][128 m][8] f16
  char* Bgl = smem + 16384;                // [8 row][128 words], col^((row&1)<<4)
  char* Bul = smem + 20480;
  char* szl = smem + 24576;                // [128 n][16B]

  const int nt = blockIdx.x, mt = blockIdx.y;
  const int tid = threadIdx.x;
  const int wave = tid >> 6, lane = tid & 63;
  const int lane31 = lane & 31, row_h = lane >> 5;

  const _Float16* gA = xs + (size_t)mt * 256 * 1024;

  // B staging: wave w stages qweight rows {2w, 2w+1} of the kit
  const int brow = 2 * wave + row_h;
  const int bcolw = (lane31 * 4) ^ ((brow & 1) << 4);
  const size_t bbase = (size_t)brow * INTER + nt * 128 + bcolw;

  // LDS read bases (bytes)
  const int n_loc = 32 * wave + lane31;
  const int bread = row_h * 512 + ((n_loc ^ (row_h << 4)) * 4);  // +kt*1024
  const int aread = row_h * 2048 + lane31 * 16;                  // +kt*4096+mi*512

  f32x16 accg[4], accu[4];
#pragma unroll
  for (int i = 0; i < 4; ++i) {
    accg[i] = (f32x16)0.f; accu[i] = (f32x16)0.f;
  }

  uint sg = 0, zg = 0, su = 0, zu = 0;

  for (int kit = 0; kit < HIDDEN / 64; ++kit) {        // 32 iters
    __syncthreads();
#pragma unroll
    for (int q = 0; q < 4; ++q) {
      const int c2 = (wave * 4 + q) * 64 + lane;
      async_copy16(gA + (size_t)kit * 8192 + (size_t)c2 * 8,
                   (char*)Al + (wave * 4 + q) * 1024);
    }
    {
      const size_t go = (size_t)kit * 8 * INTER + bbase;
      async_copy16(gq + go, Bgl + wave * 1024);
      async_copy16(uq + go, Bul + wave * 1024);
    }
    if (((kit & 1) == 0) && wave < 2) {
      async_copy16(szgu + (size_t)(kit >> 1) * INTER + nt * 128 + wave * 64 + lane,
                   szl + wave * 1024);
    }
    __syncthreads();
    if ((kit & 1) == 0) {
      uint4 v = *(const uint4*)(szl + n_loc * 16);
      sg = v.x; zg = v.y; su = v.z; zu = v.w;
    }
#pragma unroll
    for (int kt = 0; kt < 4; ++kt) {
      f16x8 af[4];
#pragma unroll
      for (int mi = 0; mi < 4; ++mi)
        af[mi] = *(const f16x8*)((char*)Al + kt * 4096 + aread + mi * 512);
      const uint wgw = *(const uint*)(Bgl + kt * 1024 + bread);
      const uint wuw = *(const uint*)(Bul + kt * 1024 + bread);
      const f16x8 bgf = dq8(wgw, sg, zg);
      const f16x8 buf_ = dq8(wuw, su, zu);
#pragma unroll
      for (int mi = 0; mi < 4; ++mi) {
        accg[mi] = __builtin_amdgcn_mfma_f32_32x32x16_f16(af[mi], bgf, accg[mi], 0, 0, 0);
        accu[mi] = __builtin_amdgcn_mfma_f32_32x32x16_f16(af[mi], buf_, accu[mi], 0, 0, 0);
      }
    }
  }
  // epilogue: h = silu(g)*u -> hs [T/128][I/8][128][8 perm]
  // 32x32 C/D: col=lane&31, row=(r&3)+8*(r>>2)+4*(lane>>5)
  const int kg = nt * 128 + n_loc;
  const int sub = kg & 7;
  const int pslot = ((sub & 3) << 1) | (sub >> 2);     // P^-1
  const size_t base = (size_t)(mt * (INTER / 8) + (kg >> 3)) * 1024 + pslot;
#pragma unroll
  for (int mi = 0; mi < 4; ++mi) {
#pragma unroll
    for (int r = 0; r < 16; ++r) {
      float g = accg[mi][r], u = accu[mi][r];
      float h = g / (1.f + __expf(-g)) * u;
      const int row = (r & 3) + 8 * (r >> 2) + 4 * row_h;
      const int ml = 32 * mi + row;
      hs[base + (size_t)ml * 8] = (_Float16)h;
    }
  }
}

// GEMM2: out = h @ Wd, fp32 out [T,H]. 128x128 tile, waves 2x2 (64m x 64n).
__global__ __launch_bounds__(256, 2)
void k_gemm_down(const _Float16* __restrict__ hs,
                 const uint* __restrict__ dq,
                 const uint2* __restrict__ szd,
                 float* __restrict__ out) {
  __shared__ char smem[16384 + 4096 + 1024];
  _Float16* Al = (_Float16*)smem;
  char* Bl  = smem + 16384;
  char* szl = smem + 20480;                // [128 n][8B]

  const int nt = blockIdx.x, mt = blockIdx.y;
  const int tid = threadIdx.x;
  const int wave = tid >> 6, lane = tid & 63;
  const int lane31 = lane & 31, row_h = lane >> 5;
  const int wm = wave >> 1, wn = wave & 1;

  const _Float16* gA = hs + (size_t)mt * (INTER / 8) * 1024;

  const int brow = 2 * wave + row_h;
  const int bcolw = (lane31 * 4) ^ ((brow & 1) << 4);
  const size_t bbase = (size_t)brow * HIDDEN + nt * 128 + bcolw;

  int nl[2], bread[2], aread[2];
#pragma unroll
  for (int i = 0; i < 2; ++i) {
    nl[i] = 64 * wn + 32 * i + lane31;
    bread[i] = row_h * 512 + ((nl[i] ^ (row_h << 4)) * 4);
    aread[i] = row_h * 2048 + (64 * wm + 32 * i + lane31) * 16;
  }

  f32x16 acc[2][2];
#pragma unroll
  for (int i = 0; i < 2; ++i)
#pragma unroll
    for (int j = 0; j < 2; ++j) acc[i][j] = (f32x16)0.f;

  uint s0 = 0, z0 = 0, s1 = 0, z1 = 0;

  for (int kit = 0; kit < INTER / 64; ++kit) {          // 88 iters
    __syncthreads();
#pragma unroll
    for (int q = 0; q < 4; ++q) {
      const int c2 = (wave * 4 + q) * 64 + lane;
      async_copy16(gA + (size_t)kit * 8192 + (size_t)c2 * 8,
                   (char*)Al + (wave * 4 + q) * 1024);
    }
    async_copy16(dq + (size_t)kit * 8 * HIDDEN + bbase, Bl + wave * 1024);
    if (((kit & 1) == 0) && wave == 0) {
      async_copy16(szd + (size_t)(kit >> 1) * HIDDEN + nt * 128 + lane * 2, szl);
    }
    __syncthreads();
    if ((kit & 1) == 0) {
      uint2 v0 = *(const uint2*)(szl + nl[0] * 8);
      uint2 v1 = *(const uint2*)(szl + nl[1] * 8);
      s0 = v0.x; z0 = v0.y; s1 = v1.x; z1 = v1.y;
    }
#pragma unroll
    for (int kt = 0; kt < 4; ++kt) {
      f16x8 af[2];
#pragma unroll
      for (int mi = 0; mi < 2; ++mi)
        af[mi] = *(const f16x8*)((char*)Al + kt * 4096 + aread[mi]);
      const uint w0 = *(const uint*)(Bl + kt * 1024 + bread[0]);
      const uint w1 = *(const uint*)(Bl + kt * 1024 + bread[1]);
      const f16x8 bf0 = dq8(w0, s0, z0);
      const f16x8 bf1 = dq8(w1, s1, z1);
#pragma unroll
      for (int mi = 0; mi < 2; ++mi) {
        acc[mi][0] = __builtin_amdgcn_mfma_f32_32x32x16_f16(af[mi], bf0, acc[mi][0], 0, 0, 0);
        acc[mi][1] = __builtin_amdgcn_mfma_f32_32x32x16_f16(af[mi], bf1, acc[mi][1], 0, 0, 0);
      }
    }
  }
#pragma unroll
  for (int mi = 0; mi < 2; ++mi)
#pragma unroll
    for (int ni = 0; ni < 2; ++ni) {
      const int n = nt * 128 + nl[ni];
#pragma unroll
      for (int r = 0; r < 16; ++r) {
        const int row = (r & 3) + 8 * (r >> 2) + 4 * row_h;
        const int m = mt * 128 + 64 * wm + 32 * mi + row;
        out[(size_t)m * HIDDEN + n] = acc[mi][ni][r];
      }
    }
}

extern "C" void kernel_launch(void* const* d_in, const int* in_sizes, int n_in,
                              void* d_out, int out_size, void* d_ws, size_t ws_size,
                              hipStream_t stream) {
  (void)in_sizes; (void)n_in; (void)out_size; (void)ws_size;
  const float* x  = (const float*)d_in[0];
  const uint*  gq = (const uint*)d_in[1];
  const uint*  gz = (const uint*)d_in[2];
  const float* gs = (const float*)d_in[3];
  const uint*  uq = (const uint*)d_in[4];
  const uint*  uz = (const uint*)d_in[5];
  const float* us = (const float*)d_in[6];
  const uint*  dq = (const uint*)d_in[7];
  const uint*  dz = (const uint*)d_in[8];
  const float* ds = (const float*)d_in[9];
  float* out = (float*)d_out;

  // ws: xs 32MB | hs 92.3MB | szgu 1.44MB | szd 0.72MB
  char* ws = (char*)d_ws;
  _Float16* xs  = (_Float16*)ws;
  _Float16* hs  = (_Float16*)(ws + (size_t)TOKENS * HIDDEN * 2);
  uint4* szgu = (uint4*)(ws + (size_t)TOKENS * HIDDEN * 2 + (size_t)TOKENS * INTER * 2);
  uint2* szd  = (uint2*)((char*)szgu + (size_t)16 * INTER * 16);

  k_convert_x<<<dim3(HIDDEN / 8, TOKENS / 128), 128, 0, stream>>>(x, xs);
  k_prep_szgu<<<dim3(INTER / 256, HIDDEN / 128), 256, 0, stream>>>(gz, gs, uz, us, szgu);
  k_prep_szd<<<dim3(HIDDEN / 256, INTER / 128), 256, 0, stream>>>(dz, ds, szd);
  k_gemm_gateup<<<dim3(INTER / 128, TOKENS / 128), 256, 0, stream>>>(xs, gq, uq, szgu, hs);
  k_gemm_down<<<dim3(HIDDEN / 128, TOKENS / 128), 256, 0, stream>>>(hs, dq, szd, out);
}